// Round 11
// baseline (872.410 us; speedup 1.0000x reference)
//
#include <hip/hip_runtime.h>
#include <hip/hip_bf16.h>
#include <hip/hip_cooperative_groups.h>

namespace cg = cooperative_groups;

#define N_NODES 50000
#define N_EDGES 250000
#define DIM 32
#define BLK 256
#define NTILES ((N_NODES + BLK - 1) / BLK)   /* 196 */
#define NG (N_NODES / 16)                    /* 3125, exact: 3125*16 = 50000 */

__device__ __forceinline__ float ldf(const void* p, int i, int isf32) {
    return isf32 ? ((const float*)p)[i]
                 : __bfloat162float(((const __hip_bfloat16*)p)[i]);
}
__device__ __forceinline__ int ldi(const int* ei, int i, int i64) {
    return i64 ? ei[2 * i] : ei[i];
}
__device__ __forceinline__ int clamp_idx(int v) {
    v = v < 0 ? 0 : v;
    return v >= N_NODES ? N_NODES - 1 : v;
}
__device__ __forceinline__ bool half_is_big(const void* p, int k) {
    unsigned short h = ((const unsigned short*)p)[k];
    float v = __uint_as_float(((unsigned int)h) << 16);
    return !(fabsf(v) <= 50.0f);   // huge or NaN half => fp32 buffer
}

// inclusive Hillis-Steele scan over BLK ints in LDS (8 rounds, ping-pong)
__device__ __forceinline__ int block_scan_incl(int v, int* s0, int* s1) {
    int tid = threadIdx.x;
    s0[tid] = v;
    __syncthreads();
    int* s = s0; int* d = s1;
    for (int off = 1; off < BLK; off <<= 1) {
        int xv = s[tid];
        if (tid >= off) xv += s[tid - off];
        d[tid] = xv;
        __syncthreads();
        int* t = s; s = d; d = t;
    }
    return s[tid];
}

// one GNN layer: each half-wave owns 2 nodes (independent gather chains, 1-deep
// packed prefetch -> 4+ loads in flight); P,Q accumulate in registers (no
// atomics, no barriers); phase-2 GEMV via LDS weights (conflict-free) +
// float4 same-address broadcasts of the half-wave's own stash.
__device__ void layer_body(const int2* __restrict__ packed,
                           const int* __restrict__ rowstart,
                           const float* __restrict__ hin,
                           float* __restrict__ outb,
                           const float* sW, const float* sB2,
                           const float* sR, const float* sCB,
                           float (*sX)[2][96], int last)
{
    int tid = threadIdx.x;
    int hw = tid >> 5, lane = tid & 31;
    for (int g = blockIdx.x; g < NG; g += gridDim.x) {
        int nA = g * 16 + hw;            // < 50000 always (exact tiling)
        int nB = nA + 8;
        int aS = rowstart[nA];
        int aE = (nA == N_NODES - 1) ? N_EDGES : rowstart[nA + 1];
        int bS = rowstart[nB];
        int bE = (nB == N_NODES - 1) ? N_EDGES : rowstart[nB + 1];
        float hA = hin[nA * DIM + lane];
        float hB = hin[nB * DIM + lane];
        float pA = 0.0f, qA = 0.0f, pB = 0.0f, qB = 0.0f;
        int kA = aS, kB = bS;
        int2 fA = make_int2(0, 0), fB = make_int2(0, 0);
        if (kA < aE) fA = packed[kA];
        if (kB < bE) fB = packed[kB];
        while (kA < aE || kB < bE) {
            if (kA < aE) {
                int2 c = fA;
                if (kA + 1 < aE) fA = packed[kA + 1];
                float hv = hin[c.x * DIM + lane];
                pA = fmaf(__int_as_float(c.y), hv, pA);
                qA += hv;
                ++kA;
            }
            if (kB < bE) {
                int2 c = fB;
                if (kB + 1 < bE) fB = packed[kB + 1];
                float hv = hin[c.x * DIM + lane];
                pB = fmaf(__int_as_float(c.y), hv, pB);
                qB += hv;
                ++kB;
            }
        }
        int dA = aE - aS, dB = bE - bS;
        float icA = 1.0f / (dA < 1 ? 1.0f : (float)dA);
        float icB = 1.0f / (dB < 1 ? 1.0f : (float)dB);
        pA *= icA; qA *= icA; pB *= icB; qB *= icB;
        // stash [P|Q|H] per node (own rows; same-wave order => no barrier)
        sX[hw][0][lane] = pA; sX[hw][0][32 + lane] = qA; sX[hw][0][64 + lane] = hA;
        sX[hw][1][lane] = pB; sX[hw][1][32 + lane] = qB; sX[hw][1][64 + lane] = hB;
        float accA = sCB[lane], accB = sCB[lane];
        #pragma unroll
        for (int i4 = 0; i4 < 8; ++i4) {
            float4 xpA = *(const float4*)&sX[hw][0][i4 * 4];
            float4 xqA = *(const float4*)&sX[hw][0][32 + i4 * 4];
            float4 xhA = *(const float4*)&sX[hw][0][64 + i4 * 4];
            float4 xpB = *(const float4*)&sX[hw][1][i4 * 4];
            float4 xqB = *(const float4*)&sX[hw][1][32 + i4 * 4];
            float4 xhB = *(const float4*)&sX[hw][1][64 + i4 * 4];
            const float* vpA = (const float*)&xpA;
            const float* vqA = (const float*)&xqA;
            const float* vhA = (const float*)&xhA;
            const float* vpB = (const float*)&xpB;
            const float* vqB = (const float*)&xqB;
            const float* vhB = (const float*)&xhB;
            #pragma unroll
            for (int j = 0; j < 4; ++j) {
                int i = i4 * 4 + j;
                float wv = sW[i * DIM + lane];    // stride-1, conflict-free
                float bv = sB2[i * DIM + lane];
                float rv = sR[i * DIM + lane];
                accA = fmaf(vpA[j], wv, accA);
                accA = fmaf(vqA[j], bv, accA);
                accA = fmaf(vhA[j], rv, accA);
                accB = fmaf(vpB[j], wv, accB);
                accB = fmaf(vqB[j], bv, accB);
                accB = fmaf(vhB[j], rv, accB);
            }
        }
        outb[nA * DIM + lane] = last ? accA : (accA > 0.0f ? accA : 0.0f);
        outb[nB * DIM + lane] = last ? accB : (accB > 0.0f ? accB : 0.0f);
    }
}

// phase < 0: cooperative single-launch (grid.sync between phases)
// phase 0..8: same phases as separate kernel launches (fallback)
__global__ __launch_bounds__(BLK, 4) void mega_kernel(
    const int* ei, const void* ea, const void* x,
    const void* nW, const void* nb,
    const void* lW, const void* lb, const void* rt, const void* cb,
    int2* packed, float* hrA, float* hrB,
    int* cntI, int* edge_cur, int* rowstart, int* tsum, int* tpre,
    float* out, int phase)
{
    __shared__ float sW[DIM * DIM], sB2[DIM * DIM], sR[DIM * DIM], sCB[DIM];
    __shared__ float sX[8][2][96];
    __shared__ int si0[BLK], si1[BLK];
    __shared__ int sdet;

    int tid = threadIdx.x;
    bool coop = (phase < 0);
    if (tid == 0) sdet = 0;
    __syncthreads();
    // dtype sniff round 1: ei(i64?), ea, x, nW, nb
    if (tid < 64) {
        if (ei[2 * tid + 1] != 0) atomicOr(&sdet, 2);
    } else if (tid < 128) {
        int k = tid - 64;
        if (half_is_big(ea, k) || half_is_big(ea, k + 64)) atomicOr(&sdet, 1);
    } else if (tid < 192) {
        int k = tid - 128;
        if (half_is_big(x, k) || half_is_big(x, k + 64)) atomicOr(&sdet, 4);
    } else {
        int k = tid - 192;
        if (k < 32) { if (half_is_big(nW, k)) atomicOr(&sdet, 8); }
        else        { if (half_is_big(nb, k - 32)) atomicOr(&sdet, 16); }
    }
    // sniff round 2: l1_W, l1_b, root, conv_b
    if (tid < 64) {
        if (half_is_big(lW, tid) || half_is_big(lW, tid + 64)) atomicOr(&sdet, 32);
    } else if (tid < 128) {
        int k = tid - 64;
        if (half_is_big(lb, k) || half_is_big(lb, k + 64)) atomicOr(&sdet, 64);
    } else if (tid < 192) {
        int k = tid - 128;
        if (half_is_big(rt, k) || half_is_big(rt, k + 64)) atomicOr(&sdet, 128);
    } else if (tid < 224) {
        if (half_is_big(cb, tid - 192)) atomicOr(&sdet, 256);
    }
    __syncthreads();
    int det = sdet;
    int f_ea = det & 1, i64 = ((det & 2) == 0);
    int f_x = (det >> 2) & 1, f_nW = (det >> 3) & 1, f_nb = (det >> 4) & 1;
    int f_lW = (det >> 5) & 1, f_lb = (det >> 6) & 1;
    int f_rt = (det >> 7) & 1, f_cb = (det >> 8) & 1;
    // weights -> LDS once (reused by all 3 layers in coop mode)
    for (int k2 = tid; k2 < DIM * DIM; k2 += BLK) {
        sW[k2]  = ldf(lW, k2, f_lW);
        sB2[k2] = ldf(lb, k2, f_lb);
        sR[k2]  = ldf(rt, k2, f_rt);
    }
    if (tid < DIM) sCB[tid] = ldf(cb, tid, f_cb);
    __syncthreads();

    int gid = blockIdx.x * BLK + tid;
    int gtot = gridDim.x * BLK;

    if (phase < 0 || phase == 0) {           // zero counters
        for (int g2 = gid; g2 < N_NODES; g2 += gtot) {
            cntI[g2] = 0;
            edge_cur[g2] = 0;
        }
    }
    if (coop) cg::this_grid().sync();

    if (phase < 0 || phase == 1) {           // count in-degrees + init hrA
        for (int e = gid; e < N_EDGES; e += gtot) {
            int d = clamp_idx(ldi(ei, N_EDGES + e, i64));
            atomicAdd(&cntI[d], 1);
        }
        for (int g2 = gid; g2 < N_NODES * DIM; g2 += gtot) {
            int n = g2 >> 5, dd = g2 & 31;
            float hv = fmaf(ldf(x, n, f_x), ldf(nW, dd, f_nW), ldf(nb, dd, f_nb));
            hrA[g2] = hv > 0.0f ? hv : 0.0f;   // relu(h0)
        }
    }
    if (coop) cg::this_grid().sync();

    if (phase < 0 || phase == 2) {           // tile scans
        if (blockIdx.x < NTILES) {
            int g2 = blockIdx.x * BLK + tid;
            int v = (g2 < N_NODES) ? cntI[g2] : 0;
            int incl = block_scan_incl(v, si0, si1);
            if (g2 < N_NODES) rowstart[g2] = incl - v;
            if (tid == BLK - 1) tsum[blockIdx.x] = incl;
        }
    }
    if (coop) cg::this_grid().sync();

    if (phase < 0 || phase == 3) {           // scan tile sums
        if (blockIdx.x == 0) {
            int v = (tid < NTILES) ? tsum[tid] : 0;
            int incl = block_scan_incl(v, si0, si1);
            if (tid < NTILES) tpre[tid] = incl - v;
        }
    }
    if (coop) cg::this_grid().sync();

    if (phase < 0 || phase == 4) {           // add tile prefixes
        if (blockIdx.x < NTILES) {
            int g2 = blockIdx.x * BLK + tid;
            if (g2 < N_NODES) rowstart[g2] += tpre[blockIdx.x];
        }
    }
    if (coop) cg::this_grid().sync();

    if (phase < 0 || phase == 5) {           // scatter edges into CSR
        for (int e = gid; e < N_EDGES; e += gtot) {
            int s = clamp_idx(ldi(ei, e, i64));
            int d = clamp_idx(ldi(ei, N_EDGES + e, i64));
            float a = ldf(ea, e, f_ea);
            int slot = rowstart[d] + atomicAdd(&edge_cur[d], 1);
            packed[slot] = make_int2(s, __float_as_int(a));
        }
    }
    if (coop) cg::this_grid().sync();

    if (phase < 0 || phase == 6)
        layer_body(packed, rowstart, hrA, hrB, sW, sB2, sR, sCB, sX, 0);
    if (coop) cg::this_grid().sync();
    if (phase < 0 || phase == 7)
        layer_body(packed, rowstart, hrB, hrA, sW, sB2, sR, sCB, sX, 0);
    if (coop) cg::this_grid().sync();
    if (phase < 0 || phase == 8)
        layer_body(packed, rowstart, hrA, out, sW, sB2, sR, sCB, sX, 1);
}

extern "C" void kernel_launch(void* const* d_in, const int* in_sizes, int n_in,
                              void* d_out, int out_size, void* d_ws, size_t ws_size,
                              hipStream_t stream) {
    // inputs by size pattern, skipping scalar args:
    // 50000(x), 500000(ei), 250000(ea), 32, 32, 1024, 1024, 1024, 32
    const void* p[16];
    int np_ = 0;
    for (int i = 0; i < n_in && np_ < 16; ++i)
        if (in_sizes[i] != 1) p[np_++] = d_in[i];

    const void* x      = p[0];
    const int*  ei     = (const int*)p[1];
    const void* ea     = p[2];
    const void* node_W = p[3];
    const void* node_b = p[4];
    const void* l1_W   = p[5];
    const void* l1_b   = p[6];
    const void* root   = p[7];
    const void* conv_b = p[8];
    float* out = (float*)d_out;

    const int ND = N_NODES * DIM;
    float* ws = (float*)d_ws;
    int2*  packed   = (int2*)ws;                    // E int2, 2 MB
    float* hrA      = (float*)(packed + N_EDGES);   // N*D, 6.4 MB
    float* hrB      = hrA + ND;                     // N*D, 6.4 MB
    int*   cntI     = (int*)(hrB + ND);             // N ints
    int*   edge_cur = cntI + N_NODES;               // N ints
    int*   rowstart = edge_cur + N_NODES;           // N ints
    int*   tsum     = rowstart + N_NODES;           // 256 ints
    int*   tpre     = tsum + 256;                   // 256 ints

    int maxB = 0;
    hipError_t occ = hipOccupancyMaxActiveBlocksPerMultiprocessor(&maxB, mega_kernel, BLK, 0);
    bool done = false;
    if (occ == hipSuccess && maxB > 0) {
        int grid = maxB * 256;                      // 256 CUs on MI355X
        if (grid > NG) grid = NG;
        if (grid >= NTILES) {
            const int* a0 = ei; const void* a1 = ea; const void* a2 = x;
            const void* a3 = node_W; const void* a4 = node_b;
            const void* a5 = l1_W; const void* a6 = l1_b;
            const void* a7 = root; const void* a8 = conv_b;
            int2* a9 = packed; float* a10 = hrA; float* a11 = hrB;
            int* a12 = cntI; int* a13 = edge_cur; int* a14 = rowstart;
            int* a15 = tsum; int* a16 = tpre;
            float* a17 = out; int a18 = -1;
            void* args[] = {&a0,&a1,&a2,&a3,&a4,&a5,&a6,&a7,&a8,&a9,&a10,
                            &a11,&a12,&a13,&a14,&a15,&a16,&a17,&a18};
            hipError_t rc = hipLaunchCooperativeKernel(
                mega_kernel, dim3(grid), dim3(BLK), args, 0, stream);
            if (rc == hipSuccess) done = true;
            else (void)hipGetLastError();   // clear sticky error, use fallback
        }
    }
    if (!done) {
        // deterministic fallback: same phases as separate launches
        for (int ph = 0; ph <= 8; ++ph)
            mega_kernel<<<1024, BLK, 0, stream>>>(
                ei, ea, x, node_W, node_b, l1_W, l1_b, root, conv_b,
                packed, hrA, hrB, cntI, edge_cur, rowstart, tsum, tpre, out, ph);
    }
}

// Round 12
// 254.638 us; speedup vs baseline: 3.4261x; 3.4261x over previous
//
#include <hip/hip_runtime.h>
#include <hip/hip_bf16.h>

#define N_NODES 50000
#define N_EDGES 250000
#define DIM 32
#define BLK 256
#define NTILES ((N_NODES + BLK - 1) / BLK)     /* 196 */
#define PREP_NB ((N_NODES * DIM + BLK - 1) / BLK)  /* 6250 */
#define WCONV_NB 13                            /* ceil(3104/256) */
#define NG (N_NODES / 16)                      /* 3125 exact */

__device__ __forceinline__ float ldf(const void* p, int i, int isf32) {
    return isf32 ? ((const float*)p)[i]
                 : __bfloat162float(((const __hip_bfloat16*)p)[i]);
}
__device__ __forceinline__ int ldi(const int* ei, int i, int i64) {
    return i64 ? ei[2 * i] : ei[i];
}
__device__ __forceinline__ int clamp_idx(int v) {
    v = v < 0 ? 0 : v;
    return v >= N_NODES ? N_NODES - 1 : v;
}
__device__ __forceinline__ bool half_is_big(const void* p, int k) {
    unsigned short h = ((const unsigned short*)p)[k];
    float v = __uint_as_float(((unsigned int)h) << 16);
    return !(fabsf(v) <= 50.0f);   // huge or NaN half => fp32 buffer
}
// global row start of node n = tile-local prefix + tile offset
__device__ __forceinline__ int rs(const int* __restrict__ rowstart,
                                  const int* __restrict__ tpre, int n) {
    return (n >= N_NODES) ? N_EDGES : rowstart[n] + tpre[n >> 8];
}

// prep: blocks [0,PREP_NB): sniff {ei,x,nW,nb}; count in-degrees (first 977
// blocks); init hrA = relu(x*nW+nb).
// blocks [PREP_NB, PREP_NB+WCONV_NB): sniff {lW,lb,rt,cb}, convert weights to
// fp32 wsAll = [W(1024) | B(1024) | R(1024) | CB(32)].
__global__ __launch_bounds__(BLK) void prep_kernel(
    const int* __restrict__ ei, const void* __restrict__ x,
    const void* __restrict__ nW, const void* __restrict__ nb,
    const void* __restrict__ lW, const void* __restrict__ lb,
    const void* __restrict__ rt, const void* __restrict__ cb,
    int* __restrict__ cntI, float* __restrict__ hrA, float* __restrict__ wsAll)
{
    __shared__ int sdet;
    int tid = threadIdx.x;
    if (tid == 0) sdet = 0;
    __syncthreads();

    if (blockIdx.x >= PREP_NB) {   // weight-conversion block
        if (tid < 64)       { if (half_is_big(lW, tid) || half_is_big(lW, tid + 64)) atomicOr(&sdet, 1); }
        else if (tid < 128) { int k = tid - 64;  if (half_is_big(lb, k) || half_is_big(lb, k + 64)) atomicOr(&sdet, 2); }
        else if (tid < 192) { int k = tid - 128; if (half_is_big(rt, k) || half_is_big(rt, k + 64)) atomicOr(&sdet, 4); }
        else if (tid < 224) { if (half_is_big(cb, tid - 192)) atomicOr(&sdet, 8); }
        __syncthreads();
        int fW = sdet & 1, fB = sdet & 2, fR = sdet & 4, fC = sdet & 8;
        int g = (int)(blockIdx.x - PREP_NB) * BLK + tid;
        if (g < 1024)       wsAll[g] = ldf(lW, g, fW);
        else if (g < 2048)  wsAll[g] = ldf(lb, g - 1024, fB);
        else if (g < 3072)  wsAll[g] = ldf(rt, g - 2048, fR);
        else if (g < 3104)  wsAll[g] = ldf(cb, g - 3072, fC);
        return;
    }

    // 2: ei int32 | 4: x f32 | 8: nW f32 | 16: nb f32
    if (tid < 64) {
        if (ei[2 * tid + 1] != 0) atomicOr(&sdet, 2);
    } else if (tid < 192) {
        int k = tid - 64;   // 128 halves of x
        if (half_is_big(x, k)) atomicOr(&sdet, 4);
    } else {
        int k = tid - 192;
        if (k < 32) { if (half_is_big(nW, k)) atomicOr(&sdet, 8); }
        else        { if (half_is_big(nb, k - 32)) atomicOr(&sdet, 16); }
    }
    __syncthreads();
    int i64 = ((sdet & 2) == 0);
    int f_x = sdet & 4, f_nW = sdet & 8, f_nb = sdet & 16;

    int g = blockIdx.x * BLK + tid;
    if (g < N_EDGES) {
        int d = clamp_idx(ldi(ei, N_EDGES + g, i64));
        atomicAdd(&cntI[d], 1);
    }
    if (g < N_NODES * DIM) {
        int n = g >> 5, dd = g & 31;
        float hv = fmaf(ldf(x, n, f_x), ldf(nW, dd, f_nW), ldf(nb, dd, f_nb));
        hrA[g] = hv > 0.0f ? hv : 0.0f;   // relu(h0)
    }
}

// scan 1: tile-local exclusive scan of cntI -> rowstart, tile sums -> tsum
__global__ __launch_bounds__(BLK) void scan_local_kernel(
    const int* __restrict__ cntI, int* __restrict__ rowstart, int* __restrict__ tsum)
{
    __shared__ int s0[BLK], s1[BLK];
    int t = threadIdx.x;
    int g = blockIdx.x * BLK + t;
    int v = (g < N_NODES) ? cntI[g] : 0;
    s0[t] = v;
    __syncthreads();
    int* s = s0; int* d = s1;
    for (int off = 1; off < BLK; off <<= 1) {
        int xv = s[t];
        if (t >= off) xv += s[t - off];
        d[t] = xv;
        __syncthreads();
        int* tmp = s; s = d; d = tmp;
    }
    int incl = s[t];
    if (g < N_NODES) rowstart[g] = incl - v;
    if (t == BLK - 1) tsum[blockIdx.x] = incl;
}

// scan 2: exclusive scan of the 196 tile sums -> tpre (one block)
__global__ __launch_bounds__(BLK) void scan_tsum_kernel(
    const int* __restrict__ tsum, int* __restrict__ tpre)
{
    __shared__ int s0[BLK], s1[BLK];
    int t = threadIdx.x;
    int v = (t < NTILES) ? tsum[t] : 0;
    s0[t] = v;
    __syncthreads();
    int* s = s0; int* d = s1;
    for (int off = 1; off < BLK; off <<= 1) {
        int xv = s[t];
        if (t >= off) xv += s[t - off];
        d[t] = xv;
        __syncthreads();
        int* tmp = s; s = d; d = tmp;
    }
    if (t < NTILES) tpre[t] = s[t] - v;
}

// scatter: decode ei/ea directly, slot = rs(dst)+cursor, packed=(src,bits(a))
__global__ __launch_bounds__(BLK) void scatter_kernel(
    const int* __restrict__ ei, const void* __restrict__ ea,
    const int* __restrict__ rowstart, const int* __restrict__ tpre,
    int* __restrict__ edge_cur, int2* __restrict__ packed)
{
    __shared__ int sdet;
    int tid = threadIdx.x;
    if (tid == 0) sdet = 0;
    __syncthreads();
    if (tid < 64) {
        if (ei[2 * tid + 1] != 0) atomicOr(&sdet, 2);
    } else if (tid < 192) {
        int k = tid - 64;   // 128 halves of ea
        if (half_is_big(ea, k)) atomicOr(&sdet, 1);
    }
    __syncthreads();
    int f_ea = sdet & 1, i64 = ((sdet & 2) == 0);

    int e = blockIdx.x * BLK + tid;
    if (e >= N_EDGES) return;
    int s = clamp_idx(ldi(ei, e, i64));
    int d = clamp_idx(ldi(ei, N_EDGES + e, i64));
    float a = ldf(ea, e, f_ea);
    int slot = rowstart[d] + tpre[d >> 8] + atomicAdd(&edge_cur[d], 1);
    packed[slot] = make_int2(s, __float_as_int(a));
}

// layer: block owns 16 nodes; half-wave hw owns nodes (g*16+hw, g*16+hw+8).
// Gather: P=Sum a*hr[src], Q=Sum hr[src]; 4 independent load chains in flight
// (2 edges x 2 nodes per iteration, predicated). No atomics, no barriers.
// GEMV: val = (P@W + Q@B)/c + hr@root + cb via __shfl half-wave broadcasts.
__global__ __launch_bounds__(BLK) void layer_kernel(
    const int2* __restrict__ packed, const int* __restrict__ rowstart,
    const int* __restrict__ tpre, const float* __restrict__ hin,
    const float* __restrict__ wsAll, float* __restrict__ outb, int last)
{
    __shared__ float sW[DIM * DIM], sB[DIM * DIM], sR[DIM * DIM], sCB[DIM];
    int tid = threadIdx.x;
    for (int k = tid; k < 3104; k += BLK) {
        float w = wsAll[k];
        if (k < 1024)      sW[k] = w;
        else if (k < 2048) sB[k - 1024] = w;
        else if (k < 3072) sR[k - 2048] = w;
        else               sCB[k - 3072] = w;
    }
    __syncthreads();

    int hw = tid >> 5, lane = tid & 31;
    int g = blockIdx.x;
    int nA = g * 16 + hw;          // < N_NODES (exact tiling)
    int nB = nA + 8;
    int aS = rs(rowstart, tpre, nA), aE = rs(rowstart, tpre, nA + 1);
    int bS = rs(rowstart, tpre, nB), bE = rs(rowstart, tpre, nB + 1);
    // nA+1 == nB start is fine; for nB == N_NODES-1 the +1 guard returns N_EDGES
    float hA = hin[nA * DIM + lane];
    float hB = hin[nB * DIM + lane];

    float pA = 0.0f, qA = 0.0f, pB = 0.0f, qB = 0.0f;
    int kA = aS, kB = bS;
    while (kA < aE || kB < bE) {
        bool vA0 = kA < aE,     vA1 = kA + 1 < aE;
        bool vB0 = kB < bE,     vB1 = kB + 1 < bE;
        int2 cA0 = make_int2(0, 0), cA1 = cA0, cB0 = cA0, cB1 = cA0;
        if (vA0) cA0 = packed[kA];
        if (vA1) cA1 = packed[kA + 1];
        if (vB0) cB0 = packed[kB];
        if (vB1) cB1 = packed[kB + 1];
        float h0 = vA0 ? hin[cA0.x * DIM + lane] : 0.0f;   // 4 chains in flight
        float h1 = vA1 ? hin[cA1.x * DIM + lane] : 0.0f;
        float h2 = vB0 ? hin[cB0.x * DIM + lane] : 0.0f;
        float h3 = vB1 ? hin[cB1.x * DIM + lane] : 0.0f;
        pA = fmaf(vA0 ? __int_as_float(cA0.y) : 0.0f, h0, pA); qA += h0;
        pA = fmaf(vA1 ? __int_as_float(cA1.y) : 0.0f, h1, pA); qA += h1;
        pB = fmaf(vB0 ? __int_as_float(cB0.y) : 0.0f, h2, pB); qB += h2;
        pB = fmaf(vB1 ? __int_as_float(cB1.y) : 0.0f, h3, pB); qB += h3;
        kA += 2; kB += 2;
    }
    int dA = aE - aS, dB = bE - bS;
    float icA = 1.0f / (dA < 1 ? 1.0f : (float)dA);
    float icB = 1.0f / (dB < 1 ? 1.0f : (float)dB);
    pA *= icA; qA *= icA; pB *= icB; qB *= icB;

    float accA = sCB[lane], accB = sCB[lane];
    #pragma unroll
    for (int i = 0; i < DIM; ++i) {
        float wv = sW[i * DIM + lane];      // stride-1, conflict-free
        float bv = sB[i * DIM + lane];
        float rv = sR[i * DIM + lane];
        accA = fmaf(__shfl(pA, i, 32), wv, accA);
        accA = fmaf(__shfl(qA, i, 32), bv, accA);
        accA = fmaf(__shfl(hA, i, 32), rv, accA);
        accB = fmaf(__shfl(pB, i, 32), wv, accB);
        accB = fmaf(__shfl(qB, i, 32), bv, accB);
        accB = fmaf(__shfl(hB, i, 32), rv, accB);
    }
    outb[nA * DIM + lane] = last ? accA : (accA > 0.0f ? accA : 0.0f);
    outb[nB * DIM + lane] = last ? accB : (accB > 0.0f ? accB : 0.0f);
}

extern "C" void kernel_launch(void* const* d_in, const int* in_sizes, int n_in,
                              void* d_out, int out_size, void* d_ws, size_t ws_size,
                              hipStream_t stream) {
    // inputs by size pattern, skipping scalar args:
    // 50000(x), 500000(ei), 250000(ea), 32, 32, 1024, 1024, 1024, 32
    const void* p[16];
    int np_ = 0;
    for (int i = 0; i < n_in && np_ < 16; ++i)
        if (in_sizes[i] != 1) p[np_++] = d_in[i];

    const void* x      = p[0];
    const int*  ei     = (const int*)p[1];
    const void* ea     = p[2];
    const void* node_W = p[3];
    const void* node_b = p[4];
    const void* l1_W   = p[5];
    const void* l1_b   = p[6];
    const void* root   = p[7];
    const void* conv_b = p[8];
    float* out = (float*)d_out;

    const int ND = N_NODES * DIM;
    float* ws = (float*)d_ws;
    int2*  packed   = (int2*)ws;                    // E int2, 2 MB
    float* hrA      = (float*)(packed + N_EDGES);   // N*D, 6.4 MB
    float* hrB      = hrA + ND;                     // N*D, 6.4 MB
    float* wsAll    = hrB + ND;                     // 3104 floats
    int*   cntI     = (int*)(wsAll + 3104);         // N ints (zeroed)
    int*   edge_cur = cntI + N_NODES;               // N ints (zeroed)
    int*   rowstart = edge_cur + N_NODES;           // N ints
    int*   tsum     = rowstart + N_NODES;           // 256 ints
    int*   tpre     = tsum + 256;                   // 256 ints

    (void)hipMemsetAsync(cntI, 0, (size_t)(2 * N_NODES) * sizeof(int), stream);
    prep_kernel<<<PREP_NB + WCONV_NB, BLK, 0, stream>>>(
        ei, x, node_W, node_b, l1_W, l1_b, root, conv_b, cntI, hrA, wsAll);
    scan_local_kernel<<<NTILES, BLK, 0, stream>>>(cntI, rowstart, tsum);
    scan_tsum_kernel<<<1, BLK, 0, stream>>>(tsum, tpre);
    scatter_kernel<<<(N_EDGES + BLK - 1) / BLK, BLK, 0, stream>>>(
        ei, ea, rowstart, tpre, edge_cur, packed);

    layer_kernel<<<NG, BLK, 0, stream>>>(packed, rowstart, tpre, hrA, wsAll, hrB, 0);
    layer_kernel<<<NG, BLK, 0, stream>>>(packed, rowstart, tpre, hrB, wsAll, hrA, 0);
    layer_kernel<<<NG, BLK, 0, stream>>>(packed, rowstart, tpre, hrA, wsAll, out, 1);
}

// Round 13
// 241.754 us; speedup vs baseline: 3.6087x; 1.0533x over previous
//
#include <hip/hip_runtime.h>
#include <hip/hip_bf16.h>

#define N_NODES 50000
#define N_EDGES 250000
#define DIM 32
#define BLK 256
#define NTILES 196                 /* ceil(50000/256) */
#define PREP_NB 6250               /* ceil(N*D/256) */
#define WCONV_NB 13                /* ceil(3104/256) */
#define LAYER_NB 3125              /* 16 nodes per block, exact */

__device__ __forceinline__ float ldf(const void* p, int i, int isf32) {
    return isf32 ? ((const float*)p)[i]
                 : __bfloat162float(((const __hip_bfloat16*)p)[i]);
}
__device__ __forceinline__ int ldi(const int* ei, int i, int i64) {
    return i64 ? ei[2 * i] : ei[i];
}
__device__ __forceinline__ int clamp_idx(int v) {
    v = v < 0 ? 0 : v;
    return v >= N_NODES ? N_NODES - 1 : v;
}
__device__ __forceinline__ bool half_is_big(const void* p, int k) {
    unsigned short h = ((const unsigned short*)p)[k];
    float v = __uint_as_float(((unsigned int)h) << 16);
    return !(fabsf(v) <= 50.0f);   // huge or NaN half => fp32 buffer
}

// prep: blocks [0,PREP_NB): sniff {ei,x,nW,nb}; count in-degrees (first 977
// blocks); init hrA = relu(x*nW+nb).
// blocks [PREP_NB,+WCONV_NB): sniff {lW,lb,rt,cb}; wsAll=[W|B|R|CB] fp32.
__global__ __launch_bounds__(BLK) void prep_kernel(
    const int* __restrict__ ei, const void* __restrict__ x,
    const void* __restrict__ nW, const void* __restrict__ nb,
    const void* __restrict__ lW, const void* __restrict__ lb,
    const void* __restrict__ rt, const void* __restrict__ cb,
    int* __restrict__ cntI, float* __restrict__ hrA, float* __restrict__ wsAll)
{
    __shared__ int sdet;
    int tid = threadIdx.x;
    if (tid == 0) sdet = 0;
    __syncthreads();

    if (blockIdx.x >= PREP_NB) {   // weight-conversion block
        if (tid < 64)       { if (half_is_big(lW, tid) || half_is_big(lW, tid + 64)) atomicOr(&sdet, 1); }
        else if (tid < 128) { int k = tid - 64;  if (half_is_big(lb, k) || half_is_big(lb, k + 64)) atomicOr(&sdet, 2); }
        else if (tid < 192) { int k = tid - 128; if (half_is_big(rt, k) || half_is_big(rt, k + 64)) atomicOr(&sdet, 4); }
        else if (tid < 224) { if (half_is_big(cb, tid - 192)) atomicOr(&sdet, 8); }
        __syncthreads();
        int fW = sdet & 1, fB = sdet & 2, fR = sdet & 4, fC = sdet & 8;
        int g = (int)(blockIdx.x - PREP_NB) * BLK + tid;
        if (g < 1024)       wsAll[g] = ldf(lW, g, fW);
        else if (g < 2048)  wsAll[g] = ldf(lb, g - 1024, fB);
        else if (g < 3072)  wsAll[g] = ldf(rt, g - 2048, fR);
        else if (g < 3104)  wsAll[g] = ldf(cb, g - 3072, fC);
        return;
    }

    // 2: ei int32 | 4: x f32 | 8: nW f32 | 16: nb f32
    if (tid < 64) {
        if (ei[2 * tid + 1] != 0) atomicOr(&sdet, 2);
    } else if (tid < 192) {
        int k = tid - 64;
        if (half_is_big(x, k)) atomicOr(&sdet, 4);
    } else {
        int k = tid - 192;
        if (k < 32) { if (half_is_big(nW, k)) atomicOr(&sdet, 8); }
        else        { if (half_is_big(nb, k - 32)) atomicOr(&sdet, 16); }
    }
    __syncthreads();
    int i64 = ((sdet & 2) == 0);
    int f_x = sdet & 4, f_nW = sdet & 8, f_nb = sdet & 16;

    int g = blockIdx.x * BLK + tid;
    if (g < N_EDGES) {
        int d = clamp_idx(ldi(ei, N_EDGES + g, i64));
        atomicAdd(&cntI[d], 1);
    }
    if (g < N_NODES * DIM) {
        int n = g >> 5, dd = g & 31;
        float hv = fmaf(ldf(x, n, f_x), ldf(nW, dd, f_nW), ldf(nb, dd, f_nb));
        hrA[g] = hv > 0.0f ? hv : 0.0f;   // relu(h0)
    }
}

// scan: tile-local exclusive scan of cntI -> rowstart, tile sums -> tsum
__global__ __launch_bounds__(BLK) void scan_local_kernel(
    const int* __restrict__ cntI, int* __restrict__ rowstart, int* __restrict__ tsum)
{
    __shared__ int s0[BLK], s1[BLK];
    int t = threadIdx.x;
    int g = blockIdx.x * BLK + t;
    int v = (g < N_NODES) ? cntI[g] : 0;
    s0[t] = v;
    __syncthreads();
    int* s = s0; int* d = s1;
    for (int off = 1; off < BLK; off <<= 1) {
        int xv = s[t];
        if (t >= off) xv += s[t - off];
        d[t] = xv;
        __syncthreads();
        int* tmp = s; s = d; d = tmp;
    }
    int incl = s[t];
    if (g < N_NODES) rowstart[g] = incl - v;
    if (t == BLK - 1) tsum[blockIdx.x] = incl;
}

// scatter: inline tile-sum scan (every block, LDS); materialize global CSR
// rowG[0..N_NODES]; decode ei/ea; place edges: packed[slot]=(src,bits(a)).
__global__ __launch_bounds__(BLK) void scatter_kernel(
    const int* __restrict__ ei, const void* __restrict__ ea,
    const int* __restrict__ rowstart, const int* __restrict__ tsum,
    int* __restrict__ edge_cur, int2* __restrict__ packed,
    int* __restrict__ rowG)
{
    __shared__ int sdet;
    __shared__ int stp[BLK], stx[BLK];
    int tid = threadIdx.x;
    if (tid == 0) sdet = 0;
    __syncthreads();
    if (tid < 64) {
        if (ei[2 * tid + 1] != 0) atomicOr(&sdet, 2);
    } else if (tid < 192) {
        int k = tid - 64;
        if (half_is_big(ea, k)) atomicOr(&sdet, 1);
    }
    int v = (tid < NTILES) ? tsum[tid] : 0;
    stp[tid] = v;
    __syncthreads();
    for (int off = 1; off < BLK; off <<= 1) {
        int xv = stp[tid];
        if (tid >= off) xv += stp[tid - off];
        __syncthreads();
        stp[tid] = xv;
        __syncthreads();
    }
    stx[tid] = stp[tid] - v;   // exclusive tile prefix
    __syncthreads();
    int f_ea = sdet & 1, i64 = ((sdet & 2) == 0);

    int e = blockIdx.x * BLK + tid;
    if (e <= N_NODES)
        rowG[e] = (e == N_NODES) ? N_EDGES : rowstart[e] + stx[e >> 8];
    if (e < N_EDGES) {
        int s = clamp_idx(ldi(ei, e, i64));
        int d = clamp_idx(ldi(ei, N_EDGES + e, i64));
        float a = ldf(ea, e, f_ea);
        int slot = rowstart[d] + stx[d >> 8] + atomicAdd(&edge_cur[d], 1);
        packed[slot] = make_int2(s, __float_as_int(a));
    }
}

// layer: one wave per 4 consecutive nodes (block = 4 waves = 16 nodes).
// Lane halves pair edges: half 0 -> edge 2i, half 1 -> edge 2i+1.
// ALL 16 packed loads issue first, then all 16 hr loads -> 2 latency
// exposures per wave for deg<=8 (93% of nodes); small tail loop otherwise.
// GEMV pairs nodes across halves; weights in LDS; no atomics/barriers in loop.
__global__ __launch_bounds__(BLK) void layer_kernel(
    const int2* __restrict__ packed, const int* __restrict__ rowG,
    const float* __restrict__ hin, const float* __restrict__ wsAll,
    float* __restrict__ outb, int last)
{
    __shared__ float sW[1024], sB[1024], sR[1024], sCB[DIM];
    int tid = threadIdx.x;
    for (int k = tid; k < 3104; k += BLK) {
        float w = wsAll[k];
        if (k < 1024)      sW[k] = w;
        else if (k < 2048) sB[k - 1024] = w;
        else if (k < 3072) sR[k - 2048] = w;
        else               sCB[k - 3072] = w;
    }
    __syncthreads();

    int wv = tid >> 6;          // wave 0..3
    int lane = tid & 63;
    int half = lane >> 5;       // 0: even edges, 1: odd edges
    int l32 = lane & 31;
    int n0 = blockIdx.x * 16 + wv * 4;    // nodes n0..n0+3 (< N_NODES, exact)

    int S[5];
    #pragma unroll
    for (int j = 0; j < 5; ++j) S[j] = rowG[n0 + j];

    // self rows (contiguous 256B wave loads), also early in flight
    float hl01 = hin[n0 * DIM + lane];
    float hl23 = hin[(n0 + 2) * DIM + lane];

    // batch 1: all packed loads (16 insts, 32 edges across halves)
    int2 c[4][4];
    #pragma unroll
    for (int j = 0; j < 4; ++j) {
        #pragma unroll
        for (int i = 0; i < 4; ++i) {
            int k = S[j] + 2 * i + half;
            k = k < N_EDGES ? k : N_EDGES - 1;   // always in-bounds
            c[j][i] = packed[k];
        }
    }
    // batch 2: all hr-row loads (16 insts)
    float h[4][4];
    #pragma unroll
    for (int j = 0; j < 4; ++j) {
        #pragma unroll
        for (int i = 0; i < 4; ++i)
            h[j][i] = hin[c[j][i].x * DIM + l32];
    }
    // accumulate with validity masks
    float p[4] = {0, 0, 0, 0}, q[4] = {0, 0, 0, 0};
    #pragma unroll
    for (int j = 0; j < 4; ++j) {
        #pragma unroll
        for (int i = 0; i < 4; ++i) {
            bool valid = (S[j] + 2 * i + half) < S[j + 1];
            float hv = valid ? h[j][i] : 0.0f;
            float a  = valid ? __int_as_float(c[j][i].y) : 0.0f;
            p[j] = fmaf(a, hv, p[j]);
            q[j] += hv;
        }
    }
    // tail: nodes with deg > 8 (rare)
    #pragma unroll
    for (int j = 0; j < 4; ++j) {
        for (int k = S[j] + 8 + half; k < S[j + 1]; k += 2) {
            int2 cc = packed[k];
            float hv = hin[cc.x * DIM + l32];
            p[j] = fmaf(__int_as_float(cc.y), hv, p[j]);
            q[j] += hv;
        }
    }
    // combine halves; scale by 1/deg
    #pragma unroll
    for (int j = 0; j < 4; ++j) {
        p[j] += __shfl_xor(p[j], 32);
        q[j] += __shfl_xor(q[j], 32);
        int dg = S[j + 1] - S[j];
        float ic = 1.0f / (dg < 1 ? 1.0f : (float)dg);
        p[j] *= ic;
        q[j] *= ic;
    }
    // GEMV: pair (n0,n1) on halves of one accumulator, (n2,n3) on the other
    float pl01 = half ? p[1] : p[0], ql01 = half ? q[1] : q[0];
    float pl23 = half ? p[3] : p[2], ql23 = half ? q[3] : q[2];
    float acc01 = sCB[l32], acc23 = sCB[l32];
    #pragma unroll
    for (int i = 0; i < DIM; ++i) {
        float wvv = sW[i * DIM + l32];   // stride-1, conflict-free
        float bvv = sB[i * DIM + l32];
        float rvv = sR[i * DIM + l32];
        acc01 = fmaf(__shfl(pl01, i, 32), wvv, acc01);
        acc01 = fmaf(__shfl(ql01, i, 32), bvv, acc01);
        acc01 = fmaf(__shfl(hl01, i, 32), rvv, acc01);
        acc23 = fmaf(__shfl(pl23, i, 32), wvv, acc23);
        acc23 = fmaf(__shfl(ql23, i, 32), bvv, acc23);
        acc23 = fmaf(__shfl(hl23, i, 32), rvv, acc23);
    }
    if (!last) {
        acc01 = acc01 > 0.0f ? acc01 : 0.0f;
        acc23 = acc23 > 0.0f ? acc23 : 0.0f;
    }
    outb[n0 * DIM + lane] = acc01;          // rows n0,n1 (256B contiguous)
    outb[(n0 + 2) * DIM + lane] = acc23;    // rows n2,n3
}

extern "C" void kernel_launch(void* const* d_in, const int* in_sizes, int n_in,
                              void* d_out, int out_size, void* d_ws, size_t ws_size,
                              hipStream_t stream) {
    // inputs by size pattern, skipping scalar args:
    // 50000(x), 500000(ei), 250000(ea), 32, 32, 1024, 1024, 1024, 32
    const void* p[16];
    int np_ = 0;
    for (int i = 0; i < n_in && np_ < 16; ++i)
        if (in_sizes[i] != 1) p[np_++] = d_in[i];

    const void* x      = p[0];
    const int*  ei     = (const int*)p[1];
    const void* ea     = p[2];
    const void* node_W = p[3];
    const void* node_b = p[4];
    const void* l1_W   = p[5];
    const void* l1_b   = p[6];
    const void* root   = p[7];
    const void* conv_b = p[8];
    float* out = (float*)d_out;

    const int ND = N_NODES * DIM;
    float* ws = (float*)d_ws;
    int2*  packed   = (int2*)ws;                    // E int2, 2 MB
    float* hrA      = (float*)(packed + N_EDGES);   // N*D, 6.4 MB
    float* hrB      = hrA + ND;                     // N*D, 6.4 MB
    float* wsAll    = hrB + ND;                     // 3104 floats
    int*   cntI     = (int*)(wsAll + 3104);         // N ints (zeroed)
    int*   edge_cur = cntI + N_NODES;               // N ints (zeroed)
    int*   rowstart = edge_cur + N_NODES;           // N ints
    int*   tsum     = rowstart + N_NODES;           // 256 ints
    int*   rowG     = tsum + 256;                   // N+1 ints

    (void)hipMemsetAsync(cntI, 0, (size_t)(2 * N_NODES) * sizeof(int), stream);
    prep_kernel<<<PREP_NB + WCONV_NB, BLK, 0, stream>>>(
        ei, x, node_W, node_b, l1_W, l1_b, root, conv_b, cntI, hrA, wsAll);
    scan_local_kernel<<<NTILES, BLK, 0, stream>>>(cntI, rowstart, tsum);
    scatter_kernel<<<(N_EDGES + BLK - 1) / BLK, BLK, 0, stream>>>(
        ei, ea, rowstart, tsum, edge_cur, packed, rowG);

    layer_kernel<<<LAYER_NB, BLK, 0, stream>>>(packed, rowG, hrA, wsAll, hrB, 0);
    layer_kernel<<<LAYER_NB, BLK, 0, stream>>>(packed, rowG, hrB, wsAll, hrA, 0);
    layer_kernel<<<LAYER_NB, BLK, 0, stream>>>(packed, rowG, hrA, wsAll, out, 1);
}

// Round 14
// 165.007 us; speedup vs baseline: 5.2871x; 1.4651x over previous
//
#include <hip/hip_runtime.h>
#include <hip/hip_bf16.h>

#define N_NODES 50000
#define N_EDGES 250000
#define DIM 32
#define BLK 256
#define NTILES 196                 /* ceil(50000/256) */
#define PREP_NB 6250               /* ceil(N*D/256) */
#define WCONV_NB 25                /* ceil((3104+3072)/256) */
#define LAYER_NB 3125              /* 16 nodes per block, exact */

typedef __attribute__((ext_vector_type(8))) short short8;
typedef __attribute__((ext_vector_type(4))) float f32x4;

__device__ __forceinline__ float ldf(const void* p, int i, int isf32) {
    return isf32 ? ((const float*)p)[i]
                 : __bfloat162float(((const __hip_bfloat16*)p)[i]);
}
__device__ __forceinline__ int ldi(const int* ei, int i, int i64) {
    return i64 ? ei[2 * i] : ei[i];
}
__device__ __forceinline__ int clamp_idx(int v) {
    v = v < 0 ? 0 : v;
    return v >= N_NODES ? N_NODES - 1 : v;
}
__device__ __forceinline__ bool half_is_big(const void* p, int k) {
    unsigned short h = ((const unsigned short*)p)[k];
    float v = __uint_as_float(((unsigned int)h) << 16);
    return !(fabsf(v) <= 50.0f);   // huge or NaN half => fp32 buffer
}
__device__ __forceinline__ unsigned short bf16bits(float v) {
    __hip_bfloat16 b = __float2bfloat16(v);
    return __builtin_bit_cast(unsigned short, b);
}

// prep: blocks [0,PREP_NB): sniff {ei,x,nW,nb}; count in-degrees (first 977
// blocks); init hrA = relu(x*nW+nb).
// blocks [PREP_NB,+WCONV_NB): sniff {lW,lb,rt,cb};
//   g <  3104: wsAll=[W|B|R|CB] fp32
//   g >= 3104: wfrag = MFMA B-fragments of [W;B;R] in bf16:
//     idx=g-3104; f=idx>>9 (f=t*2+nh); ln=(idx&511)>>3; j=idx&7
//     k=t*32+(ln>>4)*8+j; n=nh*16+(ln&15); source row k of [W;B;R], col n.
__global__ __launch_bounds__(BLK) void prep_kernel(
    const int* __restrict__ ei, const void* __restrict__ x,
    const void* __restrict__ nW, const void* __restrict__ nb,
    const void* __restrict__ lW, const void* __restrict__ lb,
    const void* __restrict__ rt, const void* __restrict__ cb,
    int* __restrict__ cntI, float* __restrict__ hrA, float* __restrict__ wsAll,
    unsigned short* __restrict__ wfrag)
{
    __shared__ int sdet;
    int tid = threadIdx.x;
    if (tid == 0) sdet = 0;
    __syncthreads();

    if (blockIdx.x >= PREP_NB) {   // weight-conversion blocks
        if (tid < 64)       { if (half_is_big(lW, tid) || half_is_big(lW, tid + 64)) atomicOr(&sdet, 1); }
        else if (tid < 128) { int k = tid - 64;  if (half_is_big(lb, k) || half_is_big(lb, k + 64)) atomicOr(&sdet, 2); }
        else if (tid < 192) { int k = tid - 128; if (half_is_big(rt, k) || half_is_big(rt, k + 64)) atomicOr(&sdet, 4); }
        else if (tid < 224) { if (half_is_big(cb, tid - 192)) atomicOr(&sdet, 8); }
        __syncthreads();
        int fW = sdet & 1, fB = sdet & 2, fR = sdet & 4, fC = sdet & 8;
        int g = (int)(blockIdx.x - PREP_NB) * BLK + tid;
        if (g < 1024)       wsAll[g] = ldf(lW, g, fW);
        else if (g < 2048)  wsAll[g] = ldf(lb, g - 1024, fB);
        else if (g < 3072)  wsAll[g] = ldf(rt, g - 2048, fR);
        else if (g < 3104)  wsAll[g] = ldf(cb, g - 3072, fC);
        else if (g < 3104 + 3072) {
            int idx = g - 3104;
            int f = idx >> 9, rem = idx & 511;
            int ln = rem >> 3, j = rem & 7;
            int t = f >> 1, nh = f & 1;
            int k = t * 32 + (ln >> 4) * 8 + j;
            int n = nh * 16 + (ln & 15);
            float v;
            if (k < 32)      v = ldf(lW, k * 32 + n, fW);
            else if (k < 64) v = ldf(lb, (k - 32) * 32 + n, fB);
            else             v = ldf(rt, (k - 64) * 32 + n, fR);
            wfrag[idx] = bf16bits(v);
        }
        return;
    }

    // 2: ei int32 | 4: x f32 | 8: nW f32 | 16: nb f32
    if (tid < 64) {
        if (ei[2 * tid + 1] != 0) atomicOr(&sdet, 2);
    } else if (tid < 192) {
        int k = tid - 64;
        if (half_is_big(x, k)) atomicOr(&sdet, 4);
    } else {
        int k = tid - 192;
        if (k < 32) { if (half_is_big(nW, k)) atomicOr(&sdet, 8); }
        else        { if (half_is_big(nb, k - 32)) atomicOr(&sdet, 16); }
    }
    __syncthreads();
    int i64 = ((sdet & 2) == 0);
    int f_x = sdet & 4, f_nW = sdet & 8, f_nb = sdet & 16;

    int g = blockIdx.x * BLK + tid;
    if (g < N_EDGES) {
        int d = clamp_idx(ldi(ei, N_EDGES + g, i64));
        atomicAdd(&cntI[d], 1);
    }
    if (g < N_NODES * DIM) {
        int n = g >> 5, dd = g & 31;
        float hv = fmaf(ldf(x, n, f_x), ldf(nW, dd, f_nW), ldf(nb, dd, f_nb));
        hrA[g] = hv > 0.0f ? hv : 0.0f;   // relu(h0)
    }
}

// scan: tile-local exclusive scan of cntI -> rowstart, tile sums -> tsum
__global__ __launch_bounds__(BLK) void scan_local_kernel(
    const int* __restrict__ cntI, int* __restrict__ rowstart, int* __restrict__ tsum)
{
    __shared__ int s0[BLK], s1[BLK];
    int t = threadIdx.x;
    int g = blockIdx.x * BLK + t;
    int v = (g < N_NODES) ? cntI[g] : 0;
    s0[t] = v;
    __syncthreads();
    int* s = s0; int* d = s1;
    for (int off = 1; off < BLK; off <<= 1) {
        int xv = s[t];
        if (t >= off) xv += s[t - off];
        d[t] = xv;
        __syncthreads();
        int* tmp = s; s = d; d = tmp;
    }
    int incl = s[t];
    if (g < N_NODES) rowstart[g] = incl - v;
    if (t == BLK - 1) tsum[blockIdx.x] = incl;
}

// scatter: inline tile-sum scan; materialize rowG[0..N]; place edges
__global__ __launch_bounds__(BLK) void scatter_kernel(
    const int* __restrict__ ei, const void* __restrict__ ea,
    const int* __restrict__ rowstart, const int* __restrict__ tsum,
    int* __restrict__ edge_cur, int2* __restrict__ packed,
    int* __restrict__ rowG)
{
    __shared__ int sdet;
    __shared__ int stp[BLK], stx[BLK];
    int tid = threadIdx.x;
    if (tid == 0) sdet = 0;
    __syncthreads();
    if (tid < 64) {
        if (ei[2 * tid + 1] != 0) atomicOr(&sdet, 2);
    } else if (tid < 192) {
        int k = tid - 64;
        if (half_is_big(ea, k)) atomicOr(&sdet, 1);
    }
    int v = (tid < NTILES) ? tsum[tid] : 0;
    stp[tid] = v;
    __syncthreads();
    for (int off = 1; off < BLK; off <<= 1) {
        int xv = stp[tid];
        if (tid >= off) xv += stp[tid - off];
        __syncthreads();
        stp[tid] = xv;
        __syncthreads();
    }
    stx[tid] = stp[tid] - v;   // exclusive tile prefix
    __syncthreads();
    int f_ea = sdet & 1, i64 = ((sdet & 2) == 0);

    int e = blockIdx.x * BLK + tid;
    if (e <= N_NODES)
        rowG[e] = (e == N_NODES) ? N_EDGES : rowstart[e] + stx[e >> 8];
    if (e < N_EDGES) {
        int s = clamp_idx(ldi(ei, e, i64));
        int d = clamp_idx(ldi(ei, N_EDGES + e, i64));
        float a = ldf(ea, e, f_ea);
        int slot = rowstart[d] + stx[d >> 8] + atomicAdd(&edge_cur[d], 1);
        packed[slot] = make_int2(s, __float_as_int(a));
    }
}

// layer: gather identical to R13 (proven). GEMV replaced by MFMA:
// A = [P|Q|H] per node (16 x 96, bf16 LDS stash), B = wfrag (96 x 32 bf16),
// 3 K-slices x 2 N-halves of mfma_f32_16x16x32_bf16, fp32 accumulate.
__global__ __launch_bounds__(BLK) void layer_kernel(
    const int2* __restrict__ packed, const int* __restrict__ rowG,
    const float* __restrict__ hin, const float* __restrict__ wsAll,
    const unsigned short* __restrict__ wfrag,
    float* __restrict__ outb, int last)
{
    __shared__ __align__(16) unsigned short sAu[16 * 96];  // [node][k] bf16
    int tid = threadIdx.x;
    int wv = tid >> 6;          // wave 0..3
    int lane = tid & 63;
    int half = lane >> 5;       // 0: even edges, 1: odd edges
    int l32 = lane & 31;
    int n0 = blockIdx.x * 16 + wv * 4;    // nodes n0..n0+3 (< N_NODES, exact)

    int S[5];
    #pragma unroll
    for (int j = 0; j < 5; ++j) S[j] = rowG[n0 + j];

    float hl01 = hin[n0 * DIM + lane];          // nodes n0,n1
    float hl23 = hin[(n0 + 2) * DIM + lane];    // nodes n2,n3

    int2 c[4][4];
    #pragma unroll
    for (int j = 0; j < 4; ++j) {
        #pragma unroll
        for (int i = 0; i < 4; ++i) {
            int k = S[j] + 2 * i + half;
            k = k < N_EDGES ? k : N_EDGES - 1;
            c[j][i] = packed[k];
        }
    }
    float h[4][4];
    #pragma unroll
    for (int j = 0; j < 4; ++j) {
        #pragma unroll
        for (int i = 0; i < 4; ++i)
            h[j][i] = hin[c[j][i].x * DIM + l32];
    }
    float p[4] = {0, 0, 0, 0}, q[4] = {0, 0, 0, 0};
    #pragma unroll
    for (int j = 0; j < 4; ++j) {
        #pragma unroll
        for (int i = 0; i < 4; ++i) {
            bool valid = (S[j] + 2 * i + half) < S[j + 1];
            float hv = valid ? h[j][i] : 0.0f;
            float a  = valid ? __int_as_float(c[j][i].y) : 0.0f;
            p[j] = fmaf(a, hv, p[j]);
            q[j] += hv;
        }
    }
    #pragma unroll
    for (int j = 0; j < 4; ++j) {
        for (int k = S[j] + 8 + half; k < S[j + 1]; k += 2) {
            int2 cc = packed[k];
            float hv = hin[cc.x * DIM + l32];
            p[j] = fmaf(__int_as_float(cc.y), hv, p[j]);
            q[j] += hv;
        }
    }
    #pragma unroll
    for (int j = 0; j < 4; ++j) {
        p[j] += __shfl_xor(p[j], 32);
        q[j] += __shfl_xor(q[j], 32);
        int dg = S[j + 1] - S[j];
        float ic = 1.0f / (dg < 1 ? 1.0f : (float)dg);
        p[j] *= ic;
        q[j] *= ic;
    }
    // stash A rows: [node][0..31]=P, [32..63]=Q, [64..95]=H (bf16)
    #pragma unroll
    for (int j = 0; j < 4; ++j)
        sAu[(wv * 4 + j) * 96 + half * 32 + l32] = bf16bits(half ? q[j] : p[j]);
    sAu[(wv * 4 + (lane >> 5)) * 96 + 64 + l32] = bf16bits(hl01);
    sAu[(wv * 4 + 2 + (lane >> 5)) * 96 + 64 + l32] = bf16bits(hl23);
    __syncthreads();

    if (wv < 2) {   // wave wv handles N-half nh=wv (out cols nh*16..+15)
        int nh = wv;
        short8 bfr[3];
        #pragma unroll
        for (int t = 0; t < 3; ++t)
            bfr[t] = *(const short8*)(wfrag + ((t * 2 + nh) * 64 + lane) * 8);
        f32x4 acc = {0.0f, 0.0f, 0.0f, 0.0f};
        #pragma unroll
        for (int t = 0; t < 3; ++t) {
            short8 afr = *(const short8*)(sAu + (lane & 15) * 96 + t * 32 + (lane >> 4) * 8);
            acc = __builtin_amdgcn_mfma_f32_16x16x32_bf16(afr, bfr[t], acc, 0, 0, 0);
        }
        float cbl = wsAll[3072 + nh * 16 + (lane & 15)];
        #pragma unroll
        for (int r = 0; r < 4; ++r) {
            int row = (lane >> 4) * 4 + r;            // block-local node
            float v = acc[r] + cbl;
            if (!last) v = v > 0.0f ? v : 0.0f;
            outb[(blockIdx.x * 16 + row) * DIM + nh * 16 + (lane & 15)] = v;
        }
    }
}

extern "C" void kernel_launch(void* const* d_in, const int* in_sizes, int n_in,
                              void* d_out, int out_size, void* d_ws, size_t ws_size,
                              hipStream_t stream) {
    // inputs by size pattern, skipping scalar args:
    // 50000(x), 500000(ei), 250000(ea), 32, 32, 1024, 1024, 1024, 32
    const void* p[16];
    int np_ = 0;
    for (int i = 0; i < n_in && np_ < 16; ++i)
        if (in_sizes[i] != 1) p[np_++] = d_in[i];

    const void* x      = p[0];
    const int*  ei     = (const int*)p[1];
    const void* ea     = p[2];
    const void* node_W = p[3];
    const void* node_b = p[4];
    const void* l1_W   = p[5];
    const void* l1_b   = p[6];
    const void* root   = p[7];
    const void* conv_b = p[8];
    float* out = (float*)d_out;

    const int ND = N_NODES * DIM;
    float* ws = (float*)d_ws;
    int2*  packed   = (int2*)ws;                    // E int2, 2 MB
    float* hrA      = (float*)(packed + N_EDGES);   // N*D, 6.4 MB
    float* hrB      = hrA + ND;                     // N*D, 6.4 MB
    float* wsAll    = hrB + ND;                     // 3104 floats (16B-aligned)
    unsigned short* wfrag = (unsigned short*)(wsAll + 3104);  // 3072 bf16 (16B-aligned)
    int*   cntI     = (int*)(wfrag + 3072);         // N ints (zeroed)
    int*   edge_cur = cntI + N_NODES;               // N ints (zeroed)
    int*   rowstart = edge_cur + N_NODES;           // N ints
    int*   tsum     = rowstart + N_NODES;           // 256 ints
    int*   rowG     = tsum + 256;                   // N+1 ints

    (void)hipMemsetAsync(cntI, 0, (size_t)(2 * N_NODES) * sizeof(int), stream);
    prep_kernel<<<PREP_NB + WCONV_NB, BLK, 0, stream>>>(
        ei, x, node_W, node_b, l1_W, l1_b, root, conv_b, cntI, hrA, wsAll, wfrag);
    scan_local_kernel<<<NTILES, BLK, 0, stream>>>(cntI, rowstart, tsum);
    scatter_kernel<<<(N_EDGES + BLK - 1) / BLK, BLK, 0, stream>>>(
        ei, ea, rowstart, tsum, edge_cur, packed, rowG);

    layer_kernel<<<LAYER_NB, BLK, 0, stream>>>(packed, rowG, hrA, wsAll, wfrag, hrB, 0);
    layer_kernel<<<LAYER_NB, BLK, 0, stream>>>(packed, rowG, hrB, wsAll, wfrag, hrA, 0);
    layer_kernel<<<LAYER_NB, BLK, 0, stream>>>(packed, rowG, hrA, wsAll, wfrag, out, 1);
}